// Round 7
// baseline (193.570 us; speedup 1.0000x reference)
//
#include <hip/hip_runtime.h>

#define N_DIM 32
#define NPB 64               // nodes per bucket
#define NPB_SHIFT 6
#define NB_MAX 2048          // max buckets (n_nodes <= 131072)
#define EPB 2048             // edges per hist/partition block
#define PT 256               // threads for hist/partition (8 edges/thread)
#define CAP 2048             // k_agg chunk capacity (bucket mean ~1024)

__device__ __forceinline__ unsigned f2bf_rne(float f) {
    unsigned u = __float_as_uint(f);
    return (u + 0x7FFFu + ((u >> 16) & 1u)) >> 16;
}
__device__ __forceinline__ float bf2f(unsigned h) {
    return __uint_as_float(h << 16);
}

// ---- Pass G: Y = X @ W, packed to bf16 (row = 16 uints = 64 B = 1 line) ----
__global__ __launch_bounds__(256) void k_gemm(const float* __restrict__ X,
                                              const float* __restrict__ W,
                                              unsigned* __restrict__ Y,
                                              int n_nodes) {
    __shared__ float Wlds[N_DIM * N_DIM];
    const int t = threadIdx.x;
    for (int i = t; i < N_DIM * N_DIM; i += 256) Wlds[i] = W[i];
    __syncthreads();

    const int r = blockIdx.x * 256 + t;
    if (r >= n_nodes) return;

    float x[N_DIM];
    const float4* xr = (const float4*)(X + (size_t)r * N_DIM);
#pragma unroll
    for (int i = 0; i < N_DIM / 4; ++i) {
        float4 v = xr[i];
        x[4 * i + 0] = v.x; x[4 * i + 1] = v.y;
        x[4 * i + 2] = v.z; x[4 * i + 3] = v.w;
    }
    float acc[N_DIM];
#pragma unroll
    for (int c = 0; c < N_DIM; ++c) acc[c] = 0.0f;
#pragma unroll
    for (int k = 0; k < N_DIM; ++k) {
        const float xk = x[k];
#pragma unroll
        for (int c = 0; c < N_DIM; ++c)
            acc[c] = fmaf(xk, Wlds[k * N_DIM + c], acc[c]);
    }
    unsigned yp[16];
#pragma unroll
    for (int q = 0; q < 16; ++q)
        yp[q] = f2bf_rne(acc[2 * q]) | (f2bf_rne(acc[2 * q + 1]) << 16);
    uint4* yr = (uint4*)(Y + (size_t)r * 16);
#pragma unroll
    for (int i = 0; i < 4; ++i)
        yr[i] = make_uint4(yp[4 * i], yp[4 * i + 1], yp[4 * i + 2], yp[4 * i + 3]);
}

// ---- Pass 0: bucket histogram with LDS pre-aggregation ----
__global__ __launch_bounds__(PT) void k_bhist(const int* __restrict__ dst,
                                              int* __restrict__ gcount,
                                              int n_edges, int nb) {
    __shared__ int h[NB_MAX];
    const int t = threadIdx.x;
    for (int i = t; i < nb; i += PT) h[i] = 0;
    __syncthreads();
    const int start = blockIdx.x * EPB;
#pragma unroll
    for (int k = 0; k < EPB / PT; ++k) {
        int e = start + t + k * PT;
        if (e < n_edges) atomicAdd(&h[dst[e] >> NPB_SHIFT], 1);
    }
    __syncthreads();
    for (int i = t; i < nb; i += PT) {
        int c = h[i];
        if (c) atomicAdd(&gcount[i], c);
    }
}

// ---- Pass 0b: exclusive scan of bucket counts (1 block, nb <= 2048) ----
__global__ __launch_bounds__(1024) void k_bscan(const int* __restrict__ gcount,
                                                int* __restrict__ base,
                                                int* __restrict__ cursor,
                                                int nb) {
    __shared__ int sc[1024];
    const int t = threadIdx.x;
    const int i0 = 2 * t, i1 = 2 * t + 1;
    int v0 = (i0 < nb) ? gcount[i0] : 0;
    int v1 = (i1 < nb) ? gcount[i1] : 0;
    int s = v0 + v1;
    sc[t] = s;
    __syncthreads();
    for (int off = 1; off < 1024; off <<= 1) {
        int x = (t >= off) ? sc[t - off] : 0;
        __syncthreads();
        sc[t] += x;
        __syncthreads();
    }
    int ex = sc[t] - s;
    if (i0 < nb) { base[i0] = ex;      cursor[i0] = ex; }
    if (i1 < nb) { base[i1] = ex + v0; cursor[i1] = ex + v0; }
    if (t == 1023) base[nb] = sc[1023];
}

// ---- Pass 1: partition edges; pack src(17b) | dstLocal(6b)<<17 ----
__global__ __launch_bounds__(PT) void k_part(const int* __restrict__ src,
                                             const int* __restrict__ dst,
                                             int* __restrict__ cursor,
                                             int* __restrict__ pairs,
                                             int n_edges, int nb) {
    __shared__ int h[NB_MAX];
    __shared__ int gb[NB_MAX];
    const int t = threadIdx.x;
    for (int i = t; i < nb; i += PT) h[i] = 0;
    __syncthreads();
    const int start = blockIdx.x * EPB;

    int bw[EPB / PT];
    int rk[EPB / PT];
#pragma unroll
    for (int k = 0; k < EPB / PT; ++k) {
        int e = start + t + k * PT;
        if (e < n_edges) {
            int d = dst[e];
            int b = d >> NPB_SHIFT;
            bw[k] = b | ((d & (NPB - 1)) << 16);
            rk[k] = atomicAdd(&h[b], 1);
        } else {
            bw[k] = -1;
        }
    }
    __syncthreads();
    for (int i = t; i < nb; i += PT) {
        int c = h[i];
        gb[i] = c ? atomicAdd(&cursor[i], c) : 0;
    }
    __syncthreads();
#pragma unroll
    for (int k = 0; k < EPB / PT; ++k) {
        if (bw[k] >= 0) {
            int e = start + t + k * PT;
            int b = bw[k] & 0xFFFF;
            int dl = bw[k] >> 16;
            pairs[gb[b] + rk[k]] = src[e] | (dl << 17);
        }
    }
}

// ---- Pass 2: per-bucket LOCAL counting-sort + register accumulation ----
// No LDS float atomics. 4 lanes per node (lane l owns cols 8l..8l+7).
__device__ __forceinline__ void addv(float* acc, uint4 v) {
    acc[0] += bf2f(v.x & 0xFFFFu); acc[1] += bf2f(v.x >> 16);
    acc[2] += bf2f(v.y & 0xFFFFu); acc[3] += bf2f(v.y >> 16);
    acc[4] += bf2f(v.z & 0xFFFFu); acc[5] += bf2f(v.z >> 16);
    acc[6] += bf2f(v.w & 0xFFFFu); acc[7] += bf2f(v.w >> 16);
}

__global__ __launch_bounds__(256) void k_agg(const uint4* __restrict__ Y4,
                                             const int* __restrict__ base,
                                             const int* __restrict__ pairs,
                                             float* __restrict__ out,
                                             int n_nodes) {
    __shared__ int sp[CAP];        // packed pairs of current chunk
    __shared__ int sbin[CAP];      // srcs sorted by local node
    __shared__ int cnt[NPB];
    __shared__ int cst[NPB];       // inclusive scan of cnt
    __shared__ int cur[NPB];

    const int t = threadIdx.x;
    const int b = blockIdx.x;
    const int e0 = base[b];
    const int e1 = base[b + 1];
    const int g = t >> 2;          // local node 0..63
    const int l = t & 3;           // quarter-row (16 B)

    float acc[8];
#pragma unroll
    for (int i = 0; i < 8; ++i) acc[i] = 0.0f;

    for (int cbase = e0; cbase < e1; cbase += CAP) {
        const int n = min(CAP, e1 - cbase);
        if (t < NPB) cnt[t] = 0;
        __syncthreads();
        // load chunk + histogram (LDS int atomics)
        for (int i = t; i < n; i += 256) {
            int p = pairs[cbase + i];
            sp[i] = p;
            atomicAdd(&cnt[p >> 17], 1);
        }
        __syncthreads();
        // inclusive scan of 64 counts (Hillis-Steele)
        if (t < NPB) cst[t] = cnt[t];
        __syncthreads();
        for (int off = 1; off < NPB; off <<= 1) {
            int v = 0;
            if (t < NPB && t >= off) v = cst[t - off];
            __syncthreads();
            if (t < NPB) cst[t] += v;
            __syncthreads();
        }
        if (t < NPB) cur[t] = cst[t] - cnt[t];
        __syncthreads();
        // rank-scatter srcs into segments
        for (int i = t; i < n; i += 256) {
            int p = sp[i];
            int r = atomicAdd(&cur[p >> 17], 1);
            sbin[r] = p & 0x1FFFF;
        }
        __syncthreads();
        // each group consumes its node's segment; 8 gathers in flight
        const int s1 = cst[g];
        const int s0 = s1 - cnt[g];
        for (int e = s0; e < s1; e += 8) {
            const int m = s1 - e;
            int i0 = sbin[e];
            int i1 = sbin[e + ((m > 1) ? 1 : 0)];
            int i2 = sbin[e + ((m > 2) ? 2 : 0)];
            int i3 = sbin[e + ((m > 3) ? 3 : 0)];
            int i4 = sbin[e + ((m > 4) ? 4 : 0)];
            int i5 = sbin[e + ((m > 5) ? 5 : 0)];
            int i6 = sbin[e + ((m > 6) ? 6 : 0)];
            int i7 = sbin[e + ((m > 7) ? 7 : 0)];
            uint4 v0 = Y4[(size_t)i0 * 4 + l];
            uint4 v1 = Y4[(size_t)i1 * 4 + l];
            uint4 v2 = Y4[(size_t)i2 * 4 + l];
            uint4 v3 = Y4[(size_t)i3 * 4 + l];
            uint4 v4 = Y4[(size_t)i4 * 4 + l];
            uint4 v5 = Y4[(size_t)i5 * 4 + l];
            uint4 v6 = Y4[(size_t)i6 * 4 + l];
            uint4 v7 = Y4[(size_t)i7 * 4 + l];
            addv(acc, v0);
            if (m > 1) addv(acc, v1);
            if (m > 2) addv(acc, v2);
            if (m > 3) addv(acc, v3);
            if (m > 4) addv(acc, v4);
            if (m > 5) addv(acc, v5);
            if (m > 6) addv(acc, v6);
            if (m > 7) addv(acc, v7);
        }
        __syncthreads();           // protect sp/cnt/sbin before next chunk
    }

    const int node = b * NPB + g;
    if (node < n_nodes) {
        ((float4*)out)[(size_t)node * 8 + 2 * l] =
            make_float4(acc[0], acc[1], acc[2], acc[3]);
        ((float4*)out)[(size_t)node * 8 + 2 * l + 1] =
            make_float4(acc[4], acc[5], acc[6], acc[7]);
    }
}

extern "C" void kernel_launch(void* const* d_in, const int* in_sizes, int n_in,
                              void* d_out, int out_size, void* d_ws, size_t ws_size,
                              hipStream_t stream) {
    const float* X   = (const float*)d_in[0];
    const float* W   = (const float*)d_in[1];
    const int*   src = (const int*)d_in[2];
    const int*   dst = (const int*)d_in[3];
    float* out = (float*)d_out;

    const int n_nodes = in_sizes[0] / N_DIM;
    const int n_edges = in_sizes[2];
    const int nb = (n_nodes + NPB - 1) / NPB;      // 1563 buckets

    // workspace layout
    unsigned* Y = (unsigned*)d_ws;                    // n_nodes * 16 uints
    int* gcount = (int*)(Y + (size_t)n_nodes * 16);   // nb
    int* base   = gcount + NB_MAX;                    // nb + 1
    int* cursor = base + NB_MAX + 1;                  // nb
    int* pairs  = cursor + NB_MAX;                    // n_edges

    hipMemsetAsync(gcount, 0, (size_t)nb * sizeof(int), stream);

    const int nblk_e = (n_edges + EPB - 1) / EPB;  // 782
    k_gemm<<<(n_nodes + 255) / 256, 256, 0, stream>>>(X, W, Y, n_nodes);
    k_bhist<<<nblk_e, PT, 0, stream>>>(dst, gcount, n_edges, nb);
    k_bscan<<<1, 1024, 0, stream>>>(gcount, base, cursor, nb);
    k_part<<<nblk_e, PT, 0, stream>>>(src, dst, cursor, pairs, n_edges, nb);
    k_agg<<<nb, 256, 0, stream>>>((const uint4*)Y, base, pairs, out, n_nodes);
}

// Round 8
// 153.400 us; speedup vs baseline: 1.2619x; 1.2619x over previous
//
#include <hip/hip_runtime.h>

#define N_DIM 32
#define NPB 64               // fine bucket: nodes per bucket
#define NPB_SHIFT 6
#define NB_MAX 2048          // max fine buckets (n_nodes <= 131072)
#define NC_MAX 128           // max coarse buckets (1024 nodes each)
#define CSH 10               // coarse shift (1024 nodes)
#define EPB 4096             // edges per hist/coarse-part block
#define PT 512               // threads for hist/coarse-part (8 edges/thread)
#define CAP 2048             // k_agg chunk capacity (fine bucket mean ~1024)
#define CAPF 2048            // k_fpart chunk capacity
#define MAXCH 10             // y-grid for k_fpart (stride loop covers overflow)

__device__ __forceinline__ unsigned f2bf_rne(float f) {
    unsigned u = __float_as_uint(f);
    return (u + 0x7FFFu + ((u >> 16) & 1u)) >> 16;
}
__device__ __forceinline__ float bf2f(unsigned h) {
    return __uint_as_float(h << 16);
}

// ---- Pass G: Y = X @ W, packed to bf16 (row = 16 uints = 64 B = 1 line) ----
__global__ __launch_bounds__(256) void k_gemm(const float* __restrict__ X,
                                              const float* __restrict__ W,
                                              unsigned* __restrict__ Y,
                                              int n_nodes) {
    __shared__ float Wlds[N_DIM * N_DIM];
    const int t = threadIdx.x;
    for (int i = t; i < N_DIM * N_DIM; i += 256) Wlds[i] = W[i];
    __syncthreads();

    const int r = blockIdx.x * 256 + t;
    if (r >= n_nodes) return;

    float x[N_DIM];
    const float4* xr = (const float4*)(X + (size_t)r * N_DIM);
#pragma unroll
    for (int i = 0; i < N_DIM / 4; ++i) {
        float4 v = xr[i];
        x[4 * i + 0] = v.x; x[4 * i + 1] = v.y;
        x[4 * i + 2] = v.z; x[4 * i + 3] = v.w;
    }
    float acc[N_DIM];
#pragma unroll
    for (int c = 0; c < N_DIM; ++c) acc[c] = 0.0f;
#pragma unroll
    for (int k = 0; k < N_DIM; ++k) {
        const float xk = x[k];
#pragma unroll
        for (int c = 0; c < N_DIM; ++c)
            acc[c] = fmaf(xk, Wlds[k * N_DIM + c], acc[c]);
    }
    unsigned yp[16];
#pragma unroll
    for (int q = 0; q < 16; ++q)
        yp[q] = f2bf_rne(acc[2 * q]) | (f2bf_rne(acc[2 * q + 1]) << 16);
    uint4* yr = (uint4*)(Y + (size_t)r * 16);
#pragma unroll
    for (int i = 0; i < 4; ++i)
        yr[i] = make_uint4(yp[4 * i], yp[4 * i + 1], yp[4 * i + 2], yp[4 * i + 3]);
}

// ---- Fine histogram (1563 bins) with LDS pre-aggregation — R6 config ----
__global__ __launch_bounds__(PT) void k_fhist(const int* __restrict__ dst,
                                              int* __restrict__ gcount,
                                              int n_edges, int nb) {
    __shared__ int h[NB_MAX];
    const int t = threadIdx.x;
    for (int i = t; i < nb; i += PT) h[i] = 0;
    __syncthreads();
    const int start = blockIdx.x * EPB;
#pragma unroll
    for (int k = 0; k < EPB / PT; ++k) {
        int e = start + t + k * PT;
        if (e < n_edges) atomicAdd(&h[dst[e] >> NPB_SHIFT], 1);
    }
    __syncthreads();
    for (int i = t; i < nb; i += PT) {
        int c = h[i];
        if (c) atomicAdd(&gcount[i], c);
    }
}

// ---- Scan fine counts -> base/cursorF; derive coarse cursors; pad base ----
__global__ __launch_bounds__(1024) void k_bscan(const int* __restrict__ gcount,
                                                int* __restrict__ base,
                                                int* __restrict__ cursorF,
                                                int* __restrict__ cursorC,
                                                int nb, int ncoarse) {
    __shared__ int sc[1024];
    const int t = threadIdx.x;
    const int i0 = 2 * t, i1 = 2 * t + 1;
    int v0 = (i0 < nb) ? gcount[i0] : 0;
    int v1 = (i1 < nb) ? gcount[i1] : 0;
    int s = v0 + v1;
    sc[t] = s;
    __syncthreads();
    for (int off = 1; off < 1024; off <<= 1) {
        int x = (t >= off) ? sc[t - off] : 0;
        __syncthreads();
        sc[t] += x;
        __syncthreads();
    }
    int ex = sc[t] - s;
    if (i0 < nb) { base[i0] = ex;      cursorF[i0] = ex; }
    if (i1 < nb) { base[i1] = ex + v0; cursorF[i1] = ex + v0; }
    const int total = sc[1023];
    // pad base[nb .. 16*ncoarse] with total (for coarse range lookups)
    for (int i = nb + t; i <= 16 * ncoarse; i += 1024) base[i] = total;
    // coarse cursor: exclusive scan at fine index 16c == sc[8c-1]
    if (t < ncoarse) cursorC[t] = (t == 0) ? 0 : sc[8 * t - 1];
}

// ---- Coarse partition (98 bins): tmp[..] = src(17b) | dstLocal10<<17 ----
__global__ __launch_bounds__(PT) void k_cpart(const int* __restrict__ src,
                                              const int* __restrict__ dst,
                                              int* __restrict__ cursorC,
                                              int* __restrict__ tmp,
                                              int n_edges, int ncoarse) {
    __shared__ int h[NC_MAX];
    __shared__ int gb[NC_MAX];
    const int t = threadIdx.x;
    if (t < NC_MAX) h[t] = 0;
    __syncthreads();
    const int start = blockIdx.x * EPB;

    int vw[EPB / PT], cw[EPB / PT], rw[EPB / PT];
#pragma unroll
    for (int k = 0; k < EPB / PT; ++k) {
        int e = start + t + k * PT;
        if (e < n_edges) {
            int d = dst[e];
            int c = d >> CSH;
            cw[k] = c;
            vw[k] = src[e] | ((d & 1023) << 17);
            rw[k] = atomicAdd(&h[c], 1);
        } else {
            cw[k] = -1;
        }
    }
    __syncthreads();
    if (t < ncoarse) {
        int c = h[t];
        gb[t] = c ? atomicAdd(&cursorC[t], c) : 0;
    }
    __syncthreads();
#pragma unroll
    for (int k = 0; k < EPB / PT; ++k)
        if (cw[k] >= 0) tmp[gb[cw[k]] + rw[k]] = vw[k];
}

// ---- Fine refine: per coarse chunk, sort into 16 fine bins, coalesced out ----
__global__ __launch_bounds__(256) void k_fpart(const int* __restrict__ base,
                                               const int* __restrict__ tmp,
                                               int* __restrict__ cursorF,
                                               int* __restrict__ pairs,
                                               int ncoarse) {
    __shared__ int sp[CAPF];
    __shared__ int sbin[CAPF];
    __shared__ int cnt[16], lstart[16], cur[16], gpos[16];
    const int t = threadIdx.x;
    const int c = blockIdx.x;
    const int s0 = base[16 * c];
    const int s1 = base[16 * c + 16];

    for (int chunk = blockIdx.y; s0 + chunk * CAPF < s1; chunk += gridDim.y) {
        const int start = s0 + chunk * CAPF;
        const int n = min(CAPF, s1 - start);
        if (t < 16) cnt[t] = 0;
        __syncthreads();
        for (int i = t; i < n; i += 256) {
            int p = tmp[start + i];
            sp[i] = p;
            atomicAdd(&cnt[(p >> 23) & 15], 1);
        }
        __syncthreads();
        if (t == 0) {
            int run = 0;
            for (int f = 0; f < 16; ++f) { lstart[f] = run; cur[f] = run; run += cnt[f]; }
        }
        __syncthreads();
        for (int i = t; i < n; i += 256) {
            int p = sp[i];
            int f = (p >> 23) & 15;
            int r = atomicAdd(&cur[f], 1);
            sbin[r] = (p & 0x7FFFFF) | (f << 24);   // keep src|dl6, tag f
        }
        __syncthreads();
        if (t < 16) gpos[t] = cnt[t] ? atomicAdd(&cursorF[16 * c + t], cnt[t]) : 0;
        __syncthreads();
        for (int i = t; i < n; i += 256) {
            int e = sbin[i];
            int f = (e >> 24) & 15;
            pairs[gpos[f] + (i - lstart[f])] = e & 0x7FFFFF;
        }
        __syncthreads();
    }
}

// ---- Pass 2: per-bucket LOCAL counting-sort + register accumulation ----
__device__ __forceinline__ void addv(float* acc, uint4 v) {
    acc[0] += bf2f(v.x & 0xFFFFu); acc[1] += bf2f(v.x >> 16);
    acc[2] += bf2f(v.y & 0xFFFFu); acc[3] += bf2f(v.y >> 16);
    acc[4] += bf2f(v.z & 0xFFFFu); acc[5] += bf2f(v.z >> 16);
    acc[6] += bf2f(v.w & 0xFFFFu); acc[7] += bf2f(v.w >> 16);
}

__global__ __launch_bounds__(256) void k_agg(const uint4* __restrict__ Y4,
                                             const int* __restrict__ base,
                                             const int* __restrict__ pairs,
                                             float* __restrict__ out,
                                             int n_nodes) {
    __shared__ int sp[CAP];
    __shared__ int sbin[CAP];
    __shared__ int cnt[NPB];
    __shared__ int cst[NPB];
    __shared__ int cur[NPB];

    const int t = threadIdx.x;
    const int b = blockIdx.x;
    const int e0 = base[b];
    const int e1 = base[b + 1];
    const int g = t >> 2;          // local node 0..63
    const int l = t & 3;           // quarter-row (16 B)

    float acc[8];
#pragma unroll
    for (int i = 0; i < 8; ++i) acc[i] = 0.0f;

    for (int cbase = e0; cbase < e1; cbase += CAP) {
        const int n = min(CAP, e1 - cbase);
        if (t < NPB) cnt[t] = 0;
        __syncthreads();
        for (int i = t; i < n; i += 256) {
            int p = pairs[cbase + i];
            sp[i] = p;
            atomicAdd(&cnt[p >> 17], 1);
        }
        __syncthreads();
        if (t < NPB) cst[t] = cnt[t];
        __syncthreads();
        for (int off = 1; off < NPB; off <<= 1) {
            int v = 0;
            if (t < NPB && t >= off) v = cst[t - off];
            __syncthreads();
            if (t < NPB) cst[t] += v;
            __syncthreads();
        }
        if (t < NPB) cur[t] = cst[t] - cnt[t];
        __syncthreads();
        for (int i = t; i < n; i += 256) {
            int p = sp[i];
            int r = atomicAdd(&cur[p >> 17], 1);
            sbin[r] = p & 0x1FFFF;
        }
        __syncthreads();
        const int s1 = cst[g];
        const int s0 = s1 - cnt[g];
        for (int e = s0; e < s1; e += 4) {
            const int m = s1 - e;
            int i0 = sbin[e];
            int i1 = sbin[e + ((m > 1) ? 1 : 0)];
            int i2 = sbin[e + ((m > 2) ? 2 : 0)];
            int i3 = sbin[e + ((m > 3) ? 3 : 0)];
            uint4 v0 = Y4[(size_t)i0 * 4 + l];
            uint4 v1 = Y4[(size_t)i1 * 4 + l];
            uint4 v2 = Y4[(size_t)i2 * 4 + l];
            uint4 v3 = Y4[(size_t)i3 * 4 + l];
            addv(acc, v0);
            if (m > 1) addv(acc, v1);
            if (m > 2) addv(acc, v2);
            if (m > 3) addv(acc, v3);
        }
        __syncthreads();
    }

    const int node = b * NPB + g;
    if (node < n_nodes) {
        ((float4*)out)[(size_t)node * 8 + 2 * l] =
            make_float4(acc[0], acc[1], acc[2], acc[3]);
        ((float4*)out)[(size_t)node * 8 + 2 * l + 1] =
            make_float4(acc[4], acc[5], acc[6], acc[7]);
    }
}

extern "C" void kernel_launch(void* const* d_in, const int* in_sizes, int n_in,
                              void* d_out, int out_size, void* d_ws, size_t ws_size,
                              hipStream_t stream) {
    const float* X   = (const float*)d_in[0];
    const float* W   = (const float*)d_in[1];
    const int*   src = (const int*)d_in[2];
    const int*   dst = (const int*)d_in[3];
    float* out = (float*)d_out;

    const int n_nodes = in_sizes[0] / N_DIM;
    const int n_edges = in_sizes[2];
    const int nb = (n_nodes + NPB - 1) / NPB;        // 1563 fine buckets
    const int ncoarse = (nb + 15) / 16;              // 98 coarse buckets

    // workspace layout
    unsigned* Y  = (unsigned*)d_ws;                   // n_nodes*16 uints (6.4 MB)
    int* gcount  = (int*)(Y + (size_t)n_nodes * 16);  // NB_MAX
    int* base    = gcount + NB_MAX;                   // NB_MAX + 32 (padded)
    int* cursorF = base + NB_MAX + 32;                // NB_MAX
    int* cursorC = cursorF + NB_MAX;                  // NC_MAX
    int* tmp     = cursorC + NC_MAX;                  // n_edges
    int* pairs   = tmp + n_edges;                     // n_edges

    hipMemsetAsync(gcount, 0, (size_t)nb * sizeof(int), stream);

    const int nblk_e = (n_edges + EPB - 1) / EPB;     // 391
    k_gemm<<<(n_nodes + 255) / 256, 256, 0, stream>>>(X, W, Y, n_nodes);
    k_fhist<<<nblk_e, PT, 0, stream>>>(dst, gcount, n_edges, nb);
    k_bscan<<<1, 1024, 0, stream>>>(gcount, base, cursorF, cursorC, nb, ncoarse);
    k_cpart<<<nblk_e, PT, 0, stream>>>(src, dst, cursorC, tmp, n_edges, ncoarse);
    k_fpart<<<dim3(ncoarse, MAXCH), 256, 0, stream>>>(base, tmp, cursorF, pairs, ncoarse);
    k_agg<<<nb, 256, 0, stream>>>((const uint4*)Y, base, pairs, out, n_nodes);
}